// Round 3
// baseline (2362.832 us; speedup 1.0000x reference)
//
#include <hip/hip_runtime.h>
#include <hip/hip_bf16.h>

typedef __attribute__((ext_vector_type(8))) short bfrag8;
typedef __attribute__((ext_vector_type(4))) float f32x4;

#define DEV static __device__ __forceinline__

constexpr int B_ = 512, T_ = 256, I_ = 256, H_ = 256;
constexpr int GROUPS = 8, BPG = 32, ROWS = 64, JPB = 8;
constexpr int NTHR = 512;
constexpr int GLD = 33;    // gates LDS row stride (f32)
constexpr int DEPTH = 4;   // h ring depth

DEV unsigned short f2bf(float f) {
  __hip_bfloat16 h = __float2bfloat16(f);
  return *reinterpret_cast<unsigned short*>(&h);
}
DEV float bf2f(unsigned short u) {
  __hip_bfloat16 h;
  *reinterpret_cast<unsigned short*>(&h) = u;
  return __bfloat162float(h);
}
DEV float sigm(float x) { return 1.0f / (1.0f + __expf(-x)); }
DEV float tanh_f(float x) {
  float e = __expf(-2.0f * fabsf(x));
  float t = (1.0f - e) / (1.0f + e);
  return copysignf(t, x);
}
// 8 f32 -> bf16x8 fragment (registers only)
DEV bfrag8 cvt_frag(const float* p) {
  float4 a = *reinterpret_cast<const float4*>(p);
  float4 b = *reinterpret_cast<const float4*>(p + 4);
  bfrag8 r;
  r[0] = (short)f2bf(a.x); r[1] = (short)f2bf(a.y);
  r[2] = (short)f2bf(a.z); r[3] = (short)f2bf(a.w);
  r[4] = (short)f2bf(b.x); r[5] = (short)f2bf(b.y);
  r[6] = (short)f2bf(b.z); r[7] = (short)f2bf(b.w);
  return r;
}

// ---- device-coherent (LLC) access helpers ----
DEV void ld_hfrag(const void* p, uint4& a0, uint4& a1, uint4& a2, uint4& a3,
                  uint4& a4, uint4& a5, uint4& a6, uint4& a7) {
  asm volatile(
      "global_load_dwordx4 %0, %8, off sc0 sc1\n\t"
      "global_load_dwordx4 %1, %8, off offset:64 sc0 sc1\n\t"
      "global_load_dwordx4 %2, %8, off offset:128 sc0 sc1\n\t"
      "global_load_dwordx4 %3, %8, off offset:192 sc0 sc1\n\t"
      "global_load_dwordx4 %4, %8, off offset:256 sc0 sc1\n\t"
      "global_load_dwordx4 %5, %8, off offset:320 sc0 sc1\n\t"
      "global_load_dwordx4 %6, %8, off offset:384 sc0 sc1\n\t"
      "global_load_dwordx4 %7, %8, off offset:448 sc0 sc1\n\t"
      "s_waitcnt vmcnt(0)"
      : "=&v"(a0), "=&v"(a1), "=&v"(a2), "=&v"(a3),
        "=&v"(a4), "=&v"(a5), "=&v"(a6), "=&v"(a7)
      : "v"(p)
      : "memory");
}
DEV uint2 ld_sys_8B(const void* p) {
  uint2 r;
  asm volatile("global_load_dwordx2 %0, %1, off sc0 sc1\n\ts_waitcnt vmcnt(0)"
               : "=&v"(r) : "v"(p) : "memory");
  return r;
}
DEV void st_sys_u16(unsigned short* p, unsigned short v) {
  asm volatile("global_store_short %0, %1, off sc0 sc1" :: "v"(p), "v"(v) : "memory");
}
DEV void st_sys_u32(unsigned int* p, unsigned int v) {
  asm volatile("global_store_dword %0, %1, off sc0 sc1" :: "v"(p), "v"(v) : "memory");
}
DEV void drain_vm() { asm volatile("s_waitcnt vmcnt(0)" ::: "memory"); }
DEV int ld_flag(const int* p) {
  int v;
  asm volatile("global_load_dword %0, %1, off sc0 sc1\n\ts_waitcnt vmcnt(0)"
               : "=v"(v) : "v"(p) : "memory");
  return v;
}

__global__ __launch_bounds__(NTHR, 2) void lstm_fused(
    const float* __restrict__ x, const int* __restrict__ is_init,
    const float* __restrict__ hx, const float* __restrict__ cx,
    const float* __restrict__ W_ih, const float* __restrict__ W_hh,
    const float* __restrict__ b_ih, const float* __restrict__ b_hh,
    const float* __restrict__ ln_w, const float* __restrict__ ln_b,
    float* __restrict__ out,
    unsigned short* __restrict__ hbuf, float* __restrict__ cts,
    int* __restrict__ flagg) {
  __shared__ float gat[64 * GLD];  // gate pre-activations exchange
  __shared__ float biasl[32];

  const int tid = threadIdx.x;
  const int g = blockIdx.x & 7;
  const int mem = blockIdx.x >> 3;   // member 0..31 within group
  const int rowbase = g * ROWS;
  const int jbase = mem * JPB;

  unsigned short* hb = hbuf + g * (DEPTH * ROWS * H_);
  int* flags = flagg + g * 64;

  const int wv = tid >> 6;            // 0..7
  const int lane = tid & 63;
  const int mt = wv >> 1;             // M-tile 0..3
  const int nt = wv & 1;              // N-tile 0..1
  const int arow = mt * 16 + (lane & 15);   // batch row (A-frag)
  const int kq = lane >> 4;                 // k sub-chunk 0..3
  const int n = nt * 16 + (lane & 15);      // gate col 0..31 (B-frag)
  const int grow = (n >> 3) * 256 + jbase + (n & 7);  // global W row
  const int row = tid >> 3;  // pointwise row 0..63
  const int seg = tid & 7;   // pointwise h-col 0..7

  float4 lnw4 = *reinterpret_cast<const float4*>(ln_w + lane * 4);
  float4 lnb4 = *reinterpret_cast<const float4*>(ln_b + lane * 4);

  // ---- prologue: W fragments resident in registers ----
  bfrag8 wih[8], whh[8];
#pragma unroll
  for (int m = 0; m < 8; ++m) {
    wih[m] = cvt_frag(W_ih + grow * 256 + m * 32 + kq * 8);
    whh[m] = cvt_frag(W_hh + grow * 256 + m * 32 + kq * 8);
  }
  if (tid < 32) {
    int gr2 = (tid >> 3) * 256 + jbase + (tid & 7);
    biasl[tid] = b_ih[gr2] + b_hh[gr2];
  }
  {  // publish h_{-1} = hx into ring slot 3
    int r = tid >> 8, cc = tid & 255;
    int lr = 2 * mem + r;
    st_sys_u16(hb + 3 * ROWS * H_ + lr * H_ + cc,
               f2bf(hx[(rowbase + lr) * H_ + cc]));
  }
  float creg = cx[(rowbase + row) * H_ + jbase + seg];

  // step-0 prefetch: reset masks + x-projection
  float rmA = is_init[(rowbase + arow) * T_ + 0] ? 0.f : 1.f;
  float rmP = is_init[(rowbase + row) * T_ + 0] ? 0.f : 1.f;
  f32x4 accx = {0.f, 0.f, 0.f, 0.f};
  {
    const float* xb = x + ((size_t)(rowbase + arow) * T_ + 0) * I_ + kq * 8;
#pragma unroll
    for (int m = 0; m < 8; ++m)
      accx = __builtin_amdgcn_mfma_f32_16x16x32_bf16(cvt_frag(xb + m * 32), wih[m], accx, 0, 0, 0);
  }
  drain_vm();
  __syncthreads();
  if (tid == 0) st_sys_u32((unsigned int*)&flags[mem], 1);

  auto do_ln = [&](int tp, const unsigned short* hbase) {
    if (wv < 2) {
      int lr = 2 * mem + wv;
      int gr = rowbase + lr;
      uint2 hv = ld_sys_8B(hbase + lr * H_ + lane * 4);
      float h0 = bf2f((unsigned short)(hv.x & 0xffff));
      float h1 = bf2f((unsigned short)(hv.x >> 16));
      float h2 = bf2f((unsigned short)(hv.y & 0xffff));
      float h3 = bf2f((unsigned short)(hv.y >> 16));
      float s = h0 + h1 + h2 + h3;
      float q = h0 * h0 + h1 * h1 + h2 * h2 + h3 * h3;
#pragma unroll
      for (int m = 1; m < 64; m <<= 1) {
        s += __shfl_xor(s, m);
        q += __shfl_xor(q, m);
      }
      float mu = s * (1.0f / 256.0f);
      float var = q * (1.0f / 256.0f) - mu * mu;
      float rs = rsqrtf(var + 1e-5f);
      const float* xp = x + ((size_t)gr * T_ + tp) * I_ + lane * 4;
      float4 xv = *reinterpret_cast<const float4*>(xp);
      float4 o4;
      o4.x = (h0 - mu) * rs * lnw4.x + lnb4.x + xv.x;
      o4.y = (h1 - mu) * rs * lnw4.y + lnb4.y + xv.y;
      o4.z = (h2 - mu) * rs * lnw4.z + lnb4.z + xv.z;
      o4.w = (h3 - mu) * rs * lnw4.w + lnb4.w + xv.w;
      *reinterpret_cast<float4*>(out + ((size_t)gr * T_ + tp) * H_ + lane * 4) = o4;
    }
  };

  // ---- main loop over time ----
  for (int t = 0; t < T_; ++t) {
    // (B) wait until all 32 blocks published h_{t-1} (flag >= t+1)
    if (wv == 0 && lane < BPG) {
      const int* fp = flags + lane;
      while (true) {
        int v = ld_flag(fp);
        if (v >= t + 1) break;
        __builtin_amdgcn_s_sleep(1);
      }
    }
    __syncthreads();

    const unsigned short* hbr = hb + ((t + 3) & 3) * (ROWS * H_);  // h_{t-1}

    // (C) h-part GEMM: reg-direct A-fragments from LLC, W_hh from registers
    f32x4 acc = accx;
    {
      uint4 hf0, hf1, hf2, hf3, hf4, hf5, hf6, hf7;
      ld_hfrag(hbr + arow * H_ + kq * 8, hf0, hf1, hf2, hf3, hf4, hf5, hf6, hf7);
      unsigned km = (rmA != 0.f) ? 0xffffffffu : 0u;
#define MASK4(v) v.x &= km; v.y &= km; v.z &= km; v.w &= km
      MASK4(hf0); MASK4(hf1); MASK4(hf2); MASK4(hf3);
      MASK4(hf4); MASK4(hf5); MASK4(hf6); MASK4(hf7);
#undef MASK4
      acc = __builtin_amdgcn_mfma_f32_16x16x32_bf16(__builtin_bit_cast(bfrag8, hf0), whh[0], acc, 0, 0, 0);
      acc = __builtin_amdgcn_mfma_f32_16x16x32_bf16(__builtin_bit_cast(bfrag8, hf1), whh[1], acc, 0, 0, 0);
      acc = __builtin_amdgcn_mfma_f32_16x16x32_bf16(__builtin_bit_cast(bfrag8, hf2), whh[2], acc, 0, 0, 0);
      acc = __builtin_amdgcn_mfma_f32_16x16x32_bf16(__builtin_bit_cast(bfrag8, hf3), whh[3], acc, 0, 0, 0);
      acc = __builtin_amdgcn_mfma_f32_16x16x32_bf16(__builtin_bit_cast(bfrag8, hf4), whh[4], acc, 0, 0, 0);
      acc = __builtin_amdgcn_mfma_f32_16x16x32_bf16(__builtin_bit_cast(bfrag8, hf5), whh[5], acc, 0, 0, 0);
      acc = __builtin_amdgcn_mfma_f32_16x16x32_bf16(__builtin_bit_cast(bfrag8, hf6), whh[6], acc, 0, 0, 0);
      acc = __builtin_amdgcn_mfma_f32_16x16x32_bf16(__builtin_bit_cast(bfrag8, hf7), whh[7], acc, 0, 0, 0);
    }
    // (D) gate exchange through LDS
#pragma unroll
    for (int r = 0; r < 4; ++r)
      gat[(mt * 16 + kq * 4 + r) * GLD + n] = acc[r];
    __syncthreads();

    // (E) pointwise cell update; publish h_t
    {
      float pi = gat[row * GLD + 0 + seg] + biasl[0 + seg];
      float pf = gat[row * GLD + 8 + seg] + biasl[8 + seg];
      float pg = gat[row * GLD + 16 + seg] + biasl[16 + seg];
      float po = gat[row * GLD + 24 + seg] + biasl[24 + seg];
      float ig = sigm(pi), fg = sigm(pf), gg = tanh_f(pg), og = sigm(po);
      creg = fg * (creg * rmP) + ig * gg;
      float hn = og * tanh_f(creg);
      st_sys_u16(hb + (t & 3) * (ROWS * H_) + row * H_ + jbase + seg, f2bf(hn));
    }
    drain_vm();
    __syncthreads();
    if (tid == 0) st_sys_u32((unsigned int*)&flags[mem], t + 2);

    // (F) shadow work: next-step masks + x-projection; LN of t-1
    if (t + 1 < T_) {
      rmA = is_init[(rowbase + arow) * T_ + t + 1] ? 0.f : 1.f;
      rmP = is_init[(rowbase + row) * T_ + t + 1] ? 0.f : 1.f;
      f32x4 ax = {0.f, 0.f, 0.f, 0.f};
      const float* xb = x + ((size_t)(rowbase + arow) * T_ + (t + 1)) * I_ + kq * 8;
#pragma unroll
      for (int m = 0; m < 8; ++m)
        ax = __builtin_amdgcn_mfma_f32_16x16x32_bf16(cvt_frag(xb + m * 32), wih[m], ax, 0, 0, 0);
      accx = ax;
    }
    if (t > 0) do_ln(t - 1, hbr);
  }

  // ---- epilogue ----
  if (wv == 0 && lane < BPG) {
    const int* fp = flags + lane;
    while (ld_flag(fp) < T_ + 1) __builtin_amdgcn_s_sleep(1);
  }
  __syncthreads();
  const unsigned short* hT = hb + (((T_ - 1) & 3)) * (ROWS * H_);
  do_ln(T_ - 1, hT);
  st_sys_u32(reinterpret_cast<unsigned int*>(cts + (size_t)(rowbase + row) * H_ + jbase + seg),
             __float_as_uint(creg));
  drain_vm();
  __syncthreads();
  if (tid == 0) st_sys_u32((unsigned int*)&flags[mem], T_ + 2);
  if (wv == 0 && lane < BPG) {
    const int* fp = flags + lane;
    while (ld_flag(fp) < T_ + 2) __builtin_amdgcn_s_sleep(1);
  }
  __syncthreads();
  {  // broadcast hT, cT over the T axis (coalesced cached writes)
    int r = tid >> 8;
    int lr = 2 * mem + r;
    int gr = rowbase + lr;
    int c4 = (tid & 63) * 4;
    int tph = (tid >> 6) & 3;
    uint2 hu = ld_sys_8B(hT + lr * H_ + c4);
    float4 hv;
    hv.x = bf2f((unsigned short)(hu.x & 0xffff));
    hv.y = bf2f((unsigned short)(hu.x >> 16));
    hv.z = bf2f((unsigned short)(hu.y & 0xffff));
    hv.w = bf2f((unsigned short)(hu.y >> 16));
    uint2 ca = ld_sys_8B(cts + (size_t)gr * H_ + c4);
    uint2 cb = ld_sys_8B(cts + (size_t)gr * H_ + c4 + 2);
    float4 cv;
    cv.x = __uint_as_float(ca.x); cv.y = __uint_as_float(ca.y);
    cv.z = __uint_as_float(cb.x); cv.w = __uint_as_float(cb.y);
    float* o1 = out + (size_t)B_ * T_ * H_ + (size_t)gr * T_ * H_;
    float* o2 = o1 + (size_t)B_ * T_ * H_;
    for (int tt = tph; tt < T_; tt += 4) {
      *reinterpret_cast<float4*>(o1 + tt * H_ + c4) = hv;
      *reinterpret_cast<float4*>(o2 + tt * H_ + c4) = cv;
    }
  }
}

extern "C" void kernel_launch(void* const* d_in, const int* in_sizes, int n_in,
                              void* d_out, int out_size, void* d_ws, size_t ws_size,
                              hipStream_t stream) {
  (void)in_sizes; (void)n_in; (void)out_size; (void)ws_size;
  const float* x = (const float*)d_in[0];
  const int* is_init = (const int*)d_in[1];
  const float* hx = (const float*)d_in[2];
  const float* cx = (const float*)d_in[3];
  const float* W_ih = (const float*)d_in[4];
  const float* W_hh = (const float*)d_in[5];
  const float* b_ih = (const float*)d_in[6];
  const float* b_hh = (const float*)d_in[7];
  const float* ln_w = (const float*)d_in[8];
  const float* ln_b = (const float*)d_in[9];
  float* out = (float*)d_out;

  char* ws = (char*)d_ws;
  unsigned short* hbuf = (unsigned short*)ws;       // 8 * 4 * 64 * 256 bf16 = 1 MB
  float* cts = (float*)(ws + (1 << 20));            // 512 * 256 f32 = 512 KB
  int* flags = (int*)(ws + (1 << 20) + (512 << 10));  // 8 groups * 64 ints

  hipMemsetAsync(flags, 0, GROUPS * 64 * sizeof(int), stream);
  // 80 KB dynamic LDS: forces 1 block/CU placement (occupancy shaping only)
  lstm_fused<<<dim3(GROUPS * BPG), dim3(NTHR), 81920, stream>>>(
      x, is_init, hx, cx, W_ih, W_hh, b_ih, b_hh, ln_w, ln_b, out, hbuf, cts, flags);
}

// Round 5
// 1989.643 us; speedup vs baseline: 1.1876x; 1.1876x over previous
//
#include <hip/hip_runtime.h>
#include <hip/hip_bf16.h>

typedef __attribute__((ext_vector_type(8))) short bfrag8;
typedef __attribute__((ext_vector_type(4))) float f32x4;

#define DEV static __device__ __forceinline__

constexpr int B_ = 512, T_ = 256, I_ = 256, H_ = 256;
constexpr int GROUPS = 8, BPG = 32, ROWS = 64, JPB = 8;
constexpr int NTHR = 512;
constexpr int GLD = 33;    // gates LDS row stride (f32)
constexpr int DEPTH = 4;   // h ring depth

DEV unsigned short f2bf(float f) {
  __hip_bfloat16 h = __float2bfloat16(f);
  return *reinterpret_cast<unsigned short*>(&h);
}
DEV float bf2f(unsigned short u) {
  __hip_bfloat16 h;
  *reinterpret_cast<unsigned short*>(&h) = u;
  return __bfloat162float(h);
}
DEV float sigm(float x) { return 1.0f / (1.0f + __expf(-x)); }
DEV float tanh_f(float x) {
  float e = __expf(-2.0f * fabsf(x));
  float t = (1.0f - e) / (1.0f + e);
  return copysignf(t, x);
}
DEV bfrag8 cvt_frag(const float* p) {
  float4 a = *reinterpret_cast<const float4*>(p);
  float4 b = *reinterpret_cast<const float4*>(p + 4);
  bfrag8 r;
  r[0] = (short)f2bf(a.x); r[1] = (short)f2bf(a.y);
  r[2] = (short)f2bf(a.z); r[3] = (short)f2bf(a.w);
  r[4] = (short)f2bf(b.x); r[5] = (short)f2bf(b.y);
  r[6] = (short)f2bf(b.z); r[7] = (short)f2bf(b.w);
  return r;
}
DEV bfrag8 cvt_frag2(float4 a, float4 b) {
  bfrag8 r;
  r[0] = (short)f2bf(a.x); r[1] = (short)f2bf(a.y);
  r[2] = (short)f2bf(a.z); r[3] = (short)f2bf(a.w);
  r[4] = (short)f2bf(b.x); r[5] = (short)f2bf(b.y);
  r[6] = (short)f2bf(b.z); r[7] = (short)f2bf(b.w);
  return r;
}

// ---- device-coherent (LLC) access helpers: proven in R2/R3 ----
DEV void ld_hfrag(const void* p, uint4& a0, uint4& a1, uint4& a2, uint4& a3,
                  uint4& a4, uint4& a5, uint4& a6, uint4& a7) {
  asm volatile(
      "global_load_dwordx4 %0, %8, off sc0 sc1\n\t"
      "global_load_dwordx4 %1, %8, off offset:64 sc0 sc1\n\t"
      "global_load_dwordx4 %2, %8, off offset:128 sc0 sc1\n\t"
      "global_load_dwordx4 %3, %8, off offset:192 sc0 sc1\n\t"
      "global_load_dwordx4 %4, %8, off offset:256 sc0 sc1\n\t"
      "global_load_dwordx4 %5, %8, off offset:320 sc0 sc1\n\t"
      "global_load_dwordx4 %6, %8, off offset:384 sc0 sc1\n\t"
      "global_load_dwordx4 %7, %8, off offset:448 sc0 sc1\n\t"
      "s_waitcnt vmcnt(0)"
      : "=&v"(a0), "=&v"(a1), "=&v"(a2), "=&v"(a3),
        "=&v"(a4), "=&v"(a5), "=&v"(a6), "=&v"(a7)
      : "v"(p)
      : "memory");
}
DEV uint2 ld_sys_8B(const void* p) {
  uint2 r;
  asm volatile("global_load_dwordx2 %0, %1, off sc0 sc1\n\ts_waitcnt vmcnt(0)"
               : "=&v"(r) : "v"(p) : "memory");
  return r;
}
DEV void st_sys_u16(unsigned short* p, unsigned int v) {
  asm volatile("global_store_short %0, %1, off sc0 sc1" :: "v"(p), "v"(v) : "memory");
}
DEV void st_sys_u32(unsigned int* p, unsigned int v) {
  asm volatile("global_store_dword %0, %1, off sc0 sc1" :: "v"(p), "v"(v) : "memory");
}
DEV void drain_vm() { asm volatile("s_waitcnt vmcnt(0)" ::: "memory"); }
DEV int ld_flag(const int* p) {
  int v;
  asm volatile("global_load_dword %0, %1, off sc0 sc1\n\ts_waitcnt vmcnt(0)"
               : "=v"(v) : "v"(p) : "memory");
  return v;
}

__global__ __launch_bounds__(NTHR, 2) void lstm_fused(
    const float* __restrict__ x, const int* __restrict__ is_init,
    const float* __restrict__ hx, const float* __restrict__ cx,
    const float* __restrict__ W_ih, const float* __restrict__ W_hh,
    const float* __restrict__ b_ih, const float* __restrict__ b_hh,
    const float* __restrict__ ln_w, const float* __restrict__ ln_b,
    float* __restrict__ out,
    unsigned short* __restrict__ hbuf, float* __restrict__ cts,
    int* __restrict__ flagg) {
  extern __shared__ char occupancy_pad[];  // 80 KB, unused: forces 1 block/CU
  __shared__ unsigned short wfr[2 * 16 * 64 * 8];  // W fragments, 32 KB
  __shared__ float gat[64 * GLD];                  // gate exchange
  __shared__ float biasl[32];

  const int tid = threadIdx.x;
  const int g = blockIdx.x & 7;
  const int mem = blockIdx.x >> 3;   // member 0..31 within group
  const int rowbase = g * ROWS;
  const int jbase = mem * JPB;

  unsigned short* hb = hbuf + g * (DEPTH * ROWS * H_);
  int* flags = flagg + g * 64;

  const int wv = tid >> 6;            // 0..7
  const int lane = tid & 63;
  const int mt = wv >> 1;             // M-tile 0..3
  const int nt = wv & 1;              // N-half 0..1
  const int arow = mt * 16 + (lane & 15);   // batch row (A-frag)
  const int kq = lane >> 4;                 // k sub-chunk 0..3
  const int row = tid >> 3;  // pointwise row 0..63
  const int seg = tid & 7;   // pointwise h-col 0..7

  float4 lnw4 = *reinterpret_cast<const float4*>(ln_w + lane * 4);
  float4 lnb4 = *reinterpret_cast<const float4*>(ln_b + lane * 4);

  // W fragment read macro: lane-consecutive 16B -> one ds_read_b128
#define WFRAG(mat, m) (*reinterpret_cast<const bfrag8*>( \
    &wfr[(((mat) * 16 + (m) * 2 + nt) * 64 + lane) * 8]))

  // ---- prologue: stage W fragments into LDS (R3's validated mapping) ----
  {
#pragma unroll
    for (int i2 = 0; i2 < 4; ++i2) {
      int fid = tid * 4 + i2;              // 0..2047
      int lp = fid & 63;
      int m = (fid >> 6) & 7;
      int ntp = (fid >> 9) & 1;
      int mat = fid >> 10;
      int nn = ntp * 16 + (lp & 15);       // gate col 0..31
      int kqp = lp >> 4;
      int growp = (nn >> 3) * 256 + jbase + (nn & 7);
      const float* src = (mat ? W_hh : W_ih) + growp * 256 + m * 32 + kqp * 8;
      *reinterpret_cast<bfrag8*>(&wfr[((mat * 16 + m * 2 + ntp) * 64 + lp) * 8]) =
          cvt_frag(src);
    }
  }
  if (tid < 32) {
    int gr2 = (tid >> 3) * 256 + jbase + (tid & 7);
    biasl[tid] = b_ih[gr2] + b_hh[gr2];
  }
  {  // publish h_{-1} = hx into ring slot 3
    int r = tid >> 8, cc = tid & 255;
    int lr = 2 * mem + r;
    st_sys_u16(hb + 3 * ROWS * H_ + lr * H_ + cc,
               (unsigned int)f2bf(hx[(size_t)(rowbase + lr) * H_ + cc]));
  }
  float creg = cx[(size_t)(rowbase + row) * H_ + jbase + seg];
  drain_vm();
  __syncthreads();
  if (tid == 0) st_sys_u32((unsigned int*)&flags[mem], 1);

  // step-0: masks + x-projection (reads W frags from LDS, post-barrier)
  float rmA = is_init[(size_t)(rowbase + arow) * T_ + 0] ? 0.f : 1.f;
  float rmP = is_init[(size_t)(rowbase + row) * T_ + 0] ? 0.f : 1.f;
  f32x4 accx = {0.f, 0.f, 0.f, 0.f};
  {
    const float* xb = x + ((size_t)(rowbase + arow) * T_) * I_ + kq * 8;
#pragma unroll
    for (int m = 0; m < 8; ++m)
      accx = __builtin_amdgcn_mfma_f32_16x16x32_bf16(cvt_frag(xb + m * 32),
                                                     WFRAG(0, m), accx, 0, 0, 0);
  }

  auto do_ln = [&](int tp, const unsigned short* hbase) {
    if (wv < 2) {
      int lr = 2 * mem + wv;
      int gr = rowbase + lr;
      uint2 hv = ld_sys_8B(hbase + lr * H_ + lane * 4);
      float h0 = bf2f((unsigned short)(hv.x & 0xffff));
      float h1 = bf2f((unsigned short)(hv.x >> 16));
      float h2 = bf2f((unsigned short)(hv.y & 0xffff));
      float h3 = bf2f((unsigned short)(hv.y >> 16));
      float s = h0 + h1 + h2 + h3;
      float q = h0 * h0 + h1 * h1 + h2 * h2 + h3 * h3;
#pragma unroll
      for (int m = 1; m < 64; m <<= 1) {
        s += __shfl_xor(s, m);
        q += __shfl_xor(q, m);
      }
      float mu = s * (1.0f / 256.0f);
      float var = q * (1.0f / 256.0f) - mu * mu;
      float rs = rsqrtf(var + 1e-5f);
      const float* xp = x + ((size_t)gr * T_ + tp) * I_ + lane * 4;
      float4 xv = *reinterpret_cast<const float4*>(xp);
      float4 o4;
      o4.x = (h0 - mu) * rs * lnw4.x + lnb4.x + xv.x;
      o4.y = (h1 - mu) * rs * lnw4.y + lnb4.y + xv.y;
      o4.z = (h2 - mu) * rs * lnw4.z + lnb4.z + xv.z;
      o4.w = (h3 - mu) * rs * lnw4.w + lnb4.w + xv.w;
      *reinterpret_cast<float4*>(out + ((size_t)gr * T_ + tp) * H_ + lane * 4) = o4;
    }
  };

  // ---- main loop over time ----
  for (int t = 0; t < T_; ++t) {
    // (A) issue next-step x loads + masks (in flight across poll+GEMM)
    int tn = (t + 1 < T_) ? t + 1 : t;
    float4 xa[16];
    {
      const float* xb = x + ((size_t)(rowbase + arow) * T_ + tn) * I_ + kq * 8;
#pragma unroll
      for (int m = 0; m < 8; ++m) {
        xa[2 * m] = *reinterpret_cast<const float4*>(xb + m * 32);
        xa[2 * m + 1] = *reinterpret_cast<const float4*>(xb + m * 32 + 4);
      }
    }
    int iiA = is_init[(size_t)(rowbase + arow) * T_ + tn];
    int iiP = is_init[(size_t)(rowbase + row) * T_ + tn];

    // (B) wait until all 32 blocks published h_{t-1}
    if (wv == 0 && lane < BPG) {
      const int* fp = flags + lane;
      while (ld_flag(fp) < t + 1) __builtin_amdgcn_s_sleep(1);
    }
    __syncthreads();

    const unsigned short* hbr = hb + ((t + 3) & 3) * (ROWS * H_);  // h_{t-1}

    // (C) h-part GEMM: reg-direct A-frags from LLC, W_hh frags from LDS
    f32x4 acc = accx;
    {
      uint4 h0, h1, h2, h3, h4, h5, h6, h7;
      ld_hfrag(hbr + arow * H_ + kq * 8, h0, h1, h2, h3, h4, h5, h6, h7);
      unsigned km = (rmA != 0.f) ? 0xffffffffu : 0u;
#define MASK4(v) v.x &= km; v.y &= km; v.z &= km; v.w &= km
      MASK4(h0); MASK4(h1); MASK4(h2); MASK4(h3);
      MASK4(h4); MASK4(h5); MASK4(h6); MASK4(h7);
#undef MASK4
      acc = __builtin_amdgcn_mfma_f32_16x16x32_bf16(__builtin_bit_cast(bfrag8, h0), WFRAG(1, 0), acc, 0, 0, 0);
      acc = __builtin_amdgcn_mfma_f32_16x16x32_bf16(__builtin_bit_cast(bfrag8, h1), WFRAG(1, 1), acc, 0, 0, 0);
      acc = __builtin_amdgcn_mfma_f32_16x16x32_bf16(__builtin_bit_cast(bfrag8, h2), WFRAG(1, 2), acc, 0, 0, 0);
      acc = __builtin_amdgcn_mfma_f32_16x16x32_bf16(__builtin_bit_cast(bfrag8, h3), WFRAG(1, 3), acc, 0, 0, 0);
      acc = __builtin_amdgcn_mfma_f32_16x16x32_bf16(__builtin_bit_cast(bfrag8, h4), WFRAG(1, 4), acc, 0, 0, 0);
      acc = __builtin_amdgcn_mfma_f32_16x16x32_bf16(__builtin_bit_cast(bfrag8, h5), WFRAG(1, 5), acc, 0, 0, 0);
      acc = __builtin_amdgcn_mfma_f32_16x16x32_bf16(__builtin_bit_cast(bfrag8, h6), WFRAG(1, 6), acc, 0, 0, 0);
      acc = __builtin_amdgcn_mfma_f32_16x16x32_bf16(__builtin_bit_cast(bfrag8, h7), WFRAG(1, 7), acc, 0, 0, 0);
    }
    // (D) gate exchange through LDS (R3's validated mapping)
#pragma unroll
    for (int r = 0; r < 4; ++r)
      gat[(mt * 16 + kq * 4 + r) * GLD + nt * 16 + (lane & 15)] = acc[r];
    __syncthreads();

    // (E) pointwise cell update; publish h_t
    {
      float pi = gat[row * GLD + 0 + seg] + biasl[0 + seg];
      float pf = gat[row * GLD + 8 + seg] + biasl[8 + seg];
      float pg = gat[row * GLD + 16 + seg] + biasl[16 + seg];
      float po = gat[row * GLD + 24 + seg] + biasl[24 + seg];
      float ig = sigm(pi), fg = sigm(pf), gg = tanh_f(pg), og = sigm(po);
      creg = fg * (creg * rmP) + ig * gg;
      float hn = og * tanh_f(creg);
      st_sys_u16(hb + (t & 3) * (ROWS * H_) + row * H_ + jbase + seg,
                 (unsigned int)f2bf(hn));
    }
    drain_vm();
    __syncthreads();
    if (tid == 0) st_sys_u32((unsigned int*)&flags[mem], t + 2);

    // (F) shadow: next-step masks + x-projection (xa in flight); LN(t-1)
    if (t + 1 < T_) {
      rmA = iiA ? 0.f : 1.f;
      rmP = iiP ? 0.f : 1.f;
      f32x4 ax = {0.f, 0.f, 0.f, 0.f};
#pragma unroll
      for (int m = 0; m < 8; ++m)
        ax = __builtin_amdgcn_mfma_f32_16x16x32_bf16(
            cvt_frag2(xa[2 * m], xa[2 * m + 1]), WFRAG(0, m), ax, 0, 0, 0);
      accx = ax;
    }
    if (t > 0) do_ln(t - 1, hbr);
  }

  // ---- epilogue ----
  if (wv == 0 && lane < BPG) {
    const int* fp = flags + lane;
    while (ld_flag(fp) < T_ + 1) __builtin_amdgcn_s_sleep(1);
  }
  __syncthreads();
  const unsigned short* hT = hb + ((T_ - 1) & 3) * (ROWS * H_);
  do_ln(T_ - 1, hT);
  st_sys_u32(reinterpret_cast<unsigned int*>(cts + (size_t)(rowbase + row) * H_ + jbase + seg),
             __float_as_uint(creg));
  drain_vm();
  __syncthreads();
  if (tid == 0) st_sys_u32((unsigned int*)&flags[mem], T_ + 2);
  if (wv == 0 && lane < BPG) {
    const int* fp = flags + lane;
    while (ld_flag(fp) < T_ + 2) __builtin_amdgcn_s_sleep(1);
  }
  __syncthreads();
  {  // broadcast hT, cT over the T axis (coalesced cached writes)
    int r = tid >> 8;
    int lr = 2 * mem + r;
    int gr = rowbase + lr;
    int c4 = (tid & 63) * 4;
    int tph = (tid >> 6) & 3;
    uint2 hu = ld_sys_8B(hT + lr * H_ + c4);
    float4 hv;
    hv.x = bf2f((unsigned short)(hu.x & 0xffff));
    hv.y = bf2f((unsigned short)(hu.x >> 16));
    hv.z = bf2f((unsigned short)(hu.y & 0xffff));
    hv.w = bf2f((unsigned short)(hu.y >> 16));
    uint2 ca = ld_sys_8B(cts + (size_t)gr * H_ + c4);
    uint2 cb = ld_sys_8B(cts + (size_t)gr * H_ + c4 + 2);
    float4 cv;
    cv.x = __uint_as_float(ca.x); cv.y = __uint_as_float(ca.y);
    cv.z = __uint_as_float(cb.x); cv.w = __uint_as_float(cb.y);
    float* o1 = out + (size_t)B_ * T_ * H_ + (size_t)gr * T_ * H_;
    float* o2 = o1 + (size_t)B_ * T_ * H_;
    for (int tt = tph; tt < T_; tt += 4) {
      *reinterpret_cast<float4*>(o1 + tt * H_ + c4) = hv;
      *reinterpret_cast<float4*>(o2 + tt * H_ + c4) = cv;
    }
  }
#undef WFRAG
}

extern "C" void kernel_launch(void* const* d_in, const int* in_sizes, int n_in,
                              void* d_out, int out_size, void* d_ws, size_t ws_size,
                              hipStream_t stream) {
  (void)in_sizes; (void)n_in; (void)out_size; (void)ws_size;
  const float* x = (const float*)d_in[0];
  const int* is_init = (const int*)d_in[1];
  const float* hx = (const float*)d_in[2];
  const float* cx = (const float*)d_in[3];
  const float* W_ih = (const float*)d_in[4];
  const float* W_hh = (const float*)d_in[5];
  const float* b_ih = (const float*)d_in[6];
  const float* b_hh = (const float*)d_in[7];
  const float* ln_w = (const float*)d_in[8];
  const float* ln_b = (const float*)d_in[9];
  float* out = (float*)d_out;

  char* ws = (char*)d_ws;
  unsigned short* hbuf = (unsigned short*)ws;          // 8 * 4 * 64 * 256 bf16 = 1 MB
  float* cts = (float*)(ws + (1 << 20));               // 512 * 256 f32 = 512 KB
  int* flags = (int*)(ws + (1 << 20) + (512 << 10));   // 8 * 64 ints = 2 KB

  hipMemsetAsync(flags, 0, GROUPS * 64 * sizeof(int), stream);
  // 80 KB dynamic LDS pad (proven in R3): 1 block/CU -> 256 blocks co-resident.
  lstm_fused<<<dim3(GROUPS * BPG), dim3(NTHR), 81920, stream>>>(
      x, is_init, hx, cx, W_ih, W_hh, b_ih, b_hh, ln_w, ln_b, out, hbuf, cts, flags);
}

// Round 6
// 1879.722 us; speedup vs baseline: 1.2570x; 1.0585x over previous
//
#include <hip/hip_runtime.h>
#include <hip/hip_bf16.h>

typedef __attribute__((ext_vector_type(8))) short bfrag8;
typedef __attribute__((ext_vector_type(4))) float f32x4;

#define DEV static __device__ __forceinline__

constexpr int B_ = 512, T_ = 256, I_ = 256, H_ = 256;
constexpr int GROUPS = 8, BPG = 32, ROWS = 64, JPB = 8;
constexpr int NTHR = 512;
constexpr int GLD = 33;     // gates LDS row stride (f32)
constexpr int LDK2 = 264;   // In LDS row stride (bf16): 528B = 4 mod 32 dwords
constexpr int DEPTH = 4;    // h ring depth

DEV unsigned short f2bf(float f) {
  __hip_bfloat16 h = __float2bfloat16(f);
  return *reinterpret_cast<unsigned short*>(&h);
}
DEV float bf2f(unsigned short u) {
  __hip_bfloat16 h;
  *reinterpret_cast<unsigned short*>(&h) = u;
  return __bfloat162float(h);
}
DEV float sigm(float x) { return 1.0f / (1.0f + __expf(-x)); }
DEV float tanh_f(float x) {
  float e = __expf(-2.0f * fabsf(x));
  float t = (1.0f - e) / (1.0f + e);
  return copysignf(t, x);
}
DEV bfrag8 cvt_frag(const float* p) {
  float4 a = *reinterpret_cast<const float4*>(p);
  float4 b = *reinterpret_cast<const float4*>(p + 4);
  bfrag8 r;
  r[0] = (short)f2bf(a.x); r[1] = (short)f2bf(a.y);
  r[2] = (short)f2bf(a.z); r[3] = (short)f2bf(a.w);
  r[4] = (short)f2bf(b.x); r[5] = (short)f2bf(b.y);
  r[6] = (short)f2bf(b.z); r[7] = (short)f2bf(b.w);
  return r;
}
DEV bfrag8 cvt_frag2(float4 a, float4 b) {
  bfrag8 r;
  r[0] = (short)f2bf(a.x); r[1] = (short)f2bf(a.y);
  r[2] = (short)f2bf(a.z); r[3] = (short)f2bf(a.w);
  r[4] = (short)f2bf(b.x); r[5] = (short)f2bf(b.y);
  r[6] = (short)f2bf(b.z); r[7] = (short)f2bf(b.w);
  return r;
}

// ---- device-coherent (LLC) access helpers: proven in R2/R3/R5 ----
DEV void ld_sys_64B(const void* p, uint4& a, uint4& b, uint4& c, uint4& d) {
  asm volatile(
      "global_load_dwordx4 %0, %4, off sc0 sc1\n\t"
      "global_load_dwordx4 %1, %4, off offset:16 sc0 sc1\n\t"
      "global_load_dwordx4 %2, %4, off offset:32 sc0 sc1\n\t"
      "global_load_dwordx4 %3, %4, off offset:48 sc0 sc1\n\t"
      "s_waitcnt vmcnt(0)"
      : "=&v"(a), "=&v"(b), "=&v"(c), "=&v"(d)
      : "v"(p)
      : "memory");
}
DEV uint2 ld_sys_8B(const void* p) {
  uint2 r;
  asm volatile("global_load_dwordx2 %0, %1, off sc0 sc1\n\ts_waitcnt vmcnt(0)"
               : "=&v"(r) : "v"(p) : "memory");
  return r;
}
DEV void st_sys_u16(unsigned short* p, unsigned int v) {
  asm volatile("global_store_short %0, %1, off sc0 sc1" :: "v"(p), "v"(v) : "memory");
}
DEV void st_sys_u32(unsigned int* p, unsigned int v) {
  asm volatile("global_store_dword %0, %1, off sc0 sc1" :: "v"(p), "v"(v) : "memory");
}
DEV void drain_vm() { asm volatile("s_waitcnt vmcnt(0)" ::: "memory"); }
DEV int ld_flag(const int* p) {
  int v;
  asm volatile("global_load_dword %0, %1, off sc0 sc1\n\ts_waitcnt vmcnt(0)"
               : "=v"(v) : "v"(p) : "memory");
  return v;
}

__global__ __launch_bounds__(NTHR, 2) void lstm_fused(
    const float* __restrict__ x, const int* __restrict__ is_init,
    const float* __restrict__ hx, const float* __restrict__ cx,
    const float* __restrict__ W_ih, const float* __restrict__ W_hh,
    const float* __restrict__ b_ih, const float* __restrict__ b_hh,
    const float* __restrict__ ln_w, const float* __restrict__ ln_b,
    float* __restrict__ out,
    unsigned short* __restrict__ hbuf, float* __restrict__ cts,
    int* __restrict__ flagg) {
  extern __shared__ char occupancy_pad[];          // 12 KB pad -> 1 block/CU
  __shared__ unsigned short wfr[2 * 16 * 64 * 8];  // W fragments, 32 KB
  __shared__ unsigned short In[64 * LDK2];         // h(t-1) tile, 33 KB
  __shared__ float gat[64 * GLD];                  // gate exchange
  __shared__ float biasl[32];
  __shared__ float rml[64];

  const int tid = threadIdx.x;
  const int g = blockIdx.x & 7;
  const int mem = blockIdx.x >> 3;   // member 0..31 within group
  const int rowbase = g * ROWS;
  const int jbase = mem * JPB;

  unsigned short* hb = hbuf + g * (DEPTH * ROWS * H_);
  int* flags = flagg + g * 64;

  const int wv = tid >> 6;            // 0..7
  const int lane = tid & 63;
  const int mt = wv >> 1;             // M-tile 0..3
  const int nt = wv & 1;              // N-half 0..1
  const int kq = lane >> 4;           // k sub-chunk 0..3
  const int row = tid >> 3;  // staging/pointwise row 0..63
  const int seg = tid & 7;   // staging/pointwise col 0..7

  float4 lnw4 = *reinterpret_cast<const float4*>(ln_w + lane * 4);
  float4 lnb4 = *reinterpret_cast<const float4*>(ln_b + lane * 4);

  // W fragment read macro: lane-consecutive 16B -> one ds_read_b128
#define WFRAG(mat, m) (*reinterpret_cast<const bfrag8*>( \
    &wfr[(((mat) * 16 + (m) * 2 + nt) * 64 + lane) * 8]))

  // ---- prologue: stage W fragments into LDS (R5's validated mapping) ----
  {
#pragma unroll
    for (int i2 = 0; i2 < 4; ++i2) {
      int fid = tid * 4 + i2;              // 0..2047
      int lp = fid & 63;
      int m = (fid >> 6) & 7;
      int ntp = (fid >> 9) & 1;
      int mat = fid >> 10;
      int nn = ntp * 16 + (lp & 15);       // gate col 0..31
      int kqp = lp >> 4;
      int growp = (nn >> 3) * 256 + jbase + (nn & 7);
      const float* src = (mat ? W_hh : W_ih) + growp * 256 + m * 32 + kqp * 8;
      *reinterpret_cast<bfrag8*>(&wfr[((mat * 16 + m * 2 + ntp) * 64 + lp) * 8]) =
          cvt_frag(src);
    }
  }
  if (tid < 32) {
    int gr2 = (tid >> 3) * 256 + jbase + (tid & 7);
    biasl[tid] = b_ih[gr2] + b_hh[gr2];
  }
  {  // publish h_{-1} = hx into ring slot 3
    int r = tid >> 8, cc = tid & 255;
    int lr = 2 * mem + r;
    st_sys_u16(hb + 3 * ROWS * H_ + lr * H_ + cc,
               (unsigned int)f2bf(hx[(size_t)(rowbase + lr) * H_ + cc]));
  }
  float creg = cx[(size_t)(rowbase + row) * H_ + jbase + seg];
  drain_vm();
  __syncthreads();
  if (tid == 0) st_sys_u32((unsigned int*)&flags[mem], 1);

  // step-0: pointwise reset mask + x-projection (W frags from LDS)
  float rmP = is_init[(size_t)(rowbase + row) * T_ + 0] ? 0.f : 1.f;
  f32x4 accx = {0.f, 0.f, 0.f, 0.f};
  {
    const int arow = mt * 16 + (lane & 15);
    const float* xb = x + ((size_t)(rowbase + arow) * T_) * I_ + kq * 8;
#pragma unroll
    for (int m = 0; m < 8; ++m)
      accx = __builtin_amdgcn_mfma_f32_16x16x32_bf16(cvt_frag(xb + m * 32),
                                                     WFRAG(0, m), accx, 0, 0, 0);
  }

  // LN + skip for one (timestep tp, local row lr) pair
  auto do_ln_row = [&](int tp, int lr) {
    const unsigned short* hbase = hb + (tp & 3) * (ROWS * H_);
    int gr = rowbase + lr;
    uint2 hv = ld_sys_8B(hbase + lr * H_ + lane * 4);
    float h0 = bf2f((unsigned short)(hv.x & 0xffff));
    float h1 = bf2f((unsigned short)(hv.x >> 16));
    float h2 = bf2f((unsigned short)(hv.y & 0xffff));
    float h3 = bf2f((unsigned short)(hv.y >> 16));
    float s = h0 + h1 + h2 + h3;
    float q = h0 * h0 + h1 * h1 + h2 * h2 + h3 * h3;
#pragma unroll
    for (int m = 1; m < 64; m <<= 1) {
      s += __shfl_xor(s, m);
      q += __shfl_xor(q, m);
    }
    float mu = s * (1.0f / 256.0f);
    float var = q * (1.0f / 256.0f) - mu * mu;
    float rs = rsqrtf(var + 1e-5f);
    const float* xp = x + ((size_t)gr * T_ + tp) * I_ + lane * 4;
    float4 xv = *reinterpret_cast<const float4*>(xp);
    float4 o4;
    o4.x = (h0 - mu) * rs * lnw4.x + lnb4.x + xv.x;
    o4.y = (h1 - mu) * rs * lnw4.y + lnb4.y + xv.y;
    o4.z = (h2 - mu) * rs * lnw4.z + lnb4.z + xv.z;
    o4.w = (h3 - mu) * rs * lnw4.w + lnb4.w + xv.w;
    *reinterpret_cast<float4*>(out + ((size_t)gr * T_ + tp) * H_ + lane * 4) = o4;
  };

  // ---- main loop over time ----
  for (int t = 0; t < T_; ++t) {
    // (A) issue next-step x loads + mask prefetch; current-step row masks
    int tn = (t + 1 < T_) ? t + 1 : t;
    float4 xa[16];
    {
      const int arow = mt * 16 + (lane & 15);
      const float* xb = x + ((size_t)(rowbase + arow) * T_ + tn) * I_ + kq * 8;
#pragma unroll
      for (int m = 0; m < 8; ++m) {
        xa[2 * m] = *reinterpret_cast<const float4*>(xb + m * 32);
        xa[2 * m + 1] = *reinterpret_cast<const float4*>(xb + m * 32 + 4);
      }
    }
    int iiP = is_init[(size_t)(rowbase + row) * T_ + tn];
    if (seg == 0)
      rml[row] = is_init[(size_t)(rowbase + row) * T_ + t] ? 0.f : 1.f;

    // (B) wait until all 32 blocks published h_{t-1}
    if (wv == 0 && lane < BPG) {
      const int* fp = flags + lane;
      while (ld_flag(fp) < t + 1) __builtin_amdgcn_s_sleep(1);
    }
    __syncthreads();

    const unsigned short* hbr = hb + ((t + 3) & 3) * (ROWS * H_);  // h_{t-1}

    // (C) stage (reset-masked) h_{t-1} -> In: coalesced 64B/lane LLC reads
    {
      float rm = rml[row];
      uint4 a, b, c, d;
      ld_sys_64B(hbr + row * H_ + seg * 32, a, b, c, d);
      uint4 z = make_uint4(0, 0, 0, 0);
      if (rm == 0.0f) { a = z; b = z; c = z; d = z; }
      uint4* dst = reinterpret_cast<uint4*>(In + row * LDK2 + seg * 32);
      dst[0] = a; dst[1] = b; dst[2] = c; dst[3] = d;
    }
    __syncthreads();

    // (D) h-part GEMM: A-frags from LDS, W_hh frags from LDS, 8 MFMAs
    f32x4 acc = accx;
    {
      const unsigned short* ab = In + (mt * 16 + (lane & 15)) * LDK2 + kq * 8;
#pragma unroll
      for (int m = 0; m < 8; ++m) {
        bfrag8 a0 = *reinterpret_cast<const bfrag8*>(ab + m * 32);
        acc = __builtin_amdgcn_mfma_f32_16x16x32_bf16(a0, WFRAG(1, m), acc, 0, 0, 0);
      }
    }
#pragma unroll
    for (int r = 0; r < 4; ++r)
      gat[(mt * 16 + kq * 4 + r) * GLD + nt * 16 + (lane & 15)] = acc[r];
    __syncthreads();

    // (E) pointwise cell update; publish h_t
    {
      float pi = gat[row * GLD + 0 + seg] + biasl[0 + seg];
      float pf = gat[row * GLD + 8 + seg] + biasl[8 + seg];
      float pg = gat[row * GLD + 16 + seg] + biasl[16 + seg];
      float po = gat[row * GLD + 24 + seg] + biasl[24 + seg];
      float ig = sigm(pi), fg = sigm(pf), gg = tanh_f(pg), og = sigm(po);
      creg = fg * (creg * rmP) + ig * gg;
      float hn = og * tanh_f(creg);
      st_sys_u16(hb + (t & 3) * (ROWS * H_) + row * H_ + jbase + seg,
                 (unsigned int)f2bf(hn));
    }
    drain_vm();
    __syncthreads();
    if (tid == 0) st_sys_u32((unsigned int*)&flags[mem], t + 2);

    // (F) shadow: next-step mask + x-projection; batched LN every other step
    rmP = iiP ? 0.f : 1.f;
    if (t + 1 < T_) {
      f32x4 ax = {0.f, 0.f, 0.f, 0.f};
#pragma unroll
      for (int m = 0; m < 8; ++m)
        ax = __builtin_amdgcn_mfma_f32_16x16x32_bf16(
            cvt_frag2(xa[2 * m], xa[2 * m + 1]), WFRAG(0, m), ax, 0, 0, 0);
      accx = ax;
    }
    // batched LN: at odd t, handle timesteps {t-2, t-1} (guaranteed complete
    // by the step-t poll; ring slots live until t+2). 4 row-LNs on waves 0-3.
    if ((t & 1) && wv < 4) {
      int tp = t - 2 + (wv >> 1);
      if (tp >= 0) do_ln_row(tp, 2 * mem + (wv & 1));
    }
  }

  // ---- epilogue ----
  if (wv == 0 && lane < BPG) {
    const int* fp = flags + lane;
    while (ld_flag(fp) < T_ + 1) __builtin_amdgcn_s_sleep(1);
  }
  __syncthreads();
  // remaining LN: timestep T-1 (odd-t batches covered 0..T-2)
  if (wv < 2) do_ln_row(T_ - 1, 2 * mem + wv);
  st_sys_u32(reinterpret_cast<unsigned int*>(cts + (size_t)(rowbase + row) * H_ + jbase + seg),
             __float_as_uint(creg));
  drain_vm();
  __syncthreads();
  if (tid == 0) st_sys_u32((unsigned int*)&flags[mem], T_ + 2);
  if (wv == 0 && lane < BPG) {
    const int* fp = flags + lane;
    while (ld_flag(fp) < T_ + 2) __builtin_amdgcn_s_sleep(1);
  }
  __syncthreads();
  {  // broadcast hT, cT over the T axis (coalesced cached writes)
    const unsigned short* hT = hb + ((T_ - 1) & 3) * (ROWS * H_);
    int r = tid >> 8;
    int lr = 2 * mem + r;
    int gr = rowbase + lr;
    int c4 = (tid & 63) * 4;
    int tph = (tid >> 6) & 3;
    uint2 hu = ld_sys_8B(hT + lr * H_ + c4);
    float4 hv;
    hv.x = bf2f((unsigned short)(hu.x & 0xffff));
    hv.y = bf2f((unsigned short)(hu.x >> 16));
    hv.z = bf2f((unsigned short)(hu.y & 0xffff));
    hv.w = bf2f((unsigned short)(hu.y >> 16));
    uint2 ca = ld_sys_8B(cts + (size_t)gr * H_ + c4);
    uint2 cb = ld_sys_8B(cts + (size_t)gr * H_ + c4 + 2);
    float4 cv;
    cv.x = __uint_as_float(ca.x); cv.y = __uint_as_float(ca.y);
    cv.z = __uint_as_float(cb.x); cv.w = __uint_as_float(cb.y);
    float* o1 = out + (size_t)B_ * T_ * H_ + (size_t)gr * T_ * H_;
    float* o2 = o1 + (size_t)B_ * T_ * H_;
    for (int tt = tph; tt < T_; tt += 4) {
      *reinterpret_cast<float4*>(o1 + tt * H_ + c4) = hv;
      *reinterpret_cast<float4*>(o2 + tt * H_ + c4) = cv;
    }
  }
#undef WFRAG
}

extern "C" void kernel_launch(void* const* d_in, const int* in_sizes, int n_in,
                              void* d_out, int out_size, void* d_ws, size_t ws_size,
                              hipStream_t stream) {
  (void)in_sizes; (void)n_in; (void)out_size; (void)ws_size;
  const float* x = (const float*)d_in[0];
  const int* is_init = (const int*)d_in[1];
  const float* hx = (const float*)d_in[2];
  const float* cx = (const float*)d_in[3];
  const float* W_ih = (const float*)d_in[4];
  const float* W_hh = (const float*)d_in[5];
  const float* b_ih = (const float*)d_in[6];
  const float* b_hh = (const float*)d_in[7];
  const float* ln_w = (const float*)d_in[8];
  const float* ln_b = (const float*)d_in[9];
  float* out = (float*)d_out;

  char* ws = (char*)d_ws;
  unsigned short* hbuf = (unsigned short*)ws;          // 8 * 4 * 64 * 256 bf16 = 1 MB
  float* cts = (float*)(ws + (1 << 20));               // 512 * 256 f32 = 512 KB
  int* flags = (int*)(ws + (1 << 20) + (512 << 10));   // 8 * 64 ints = 2 KB

  hipMemsetAsync(flags, 0, GROUPS * 64 * sizeof(int), stream);
  // ~75 KB static LDS + 12 KB dynamic pad -> 1 block/CU (2 blocks won't fit).
  lstm_fused<<<dim3(GROUPS * BPG), dim3(NTHR), 12288, stream>>>(
      x, is_init, hx, cx, W_ih, W_hh, b_ih, b_hh, ln_w, ln_b, out, hbuf, cts, flags);
}

// Round 9
// 1370.910 us; speedup vs baseline: 1.7235x; 1.3711x over previous
//
#include <hip/hip_runtime.h>
#include <hip/hip_bf16.h>

typedef __attribute__((ext_vector_type(8))) short bfrag8;
typedef __attribute__((ext_vector_type(4))) float f32x4;

#define DEV static __device__ __forceinline__

constexpr int B_ = 512, T_ = 256, I_ = 256, H_ = 256;
constexpr int GROUPS = 8, BPG = 32, ROWS = 64, JPB = 8;
constexpr int NTHR = 512;
constexpr int GLD = 33;     // gates LDS row stride (f32)
constexpr int LDK2 = 264;   // In LDS row stride (bf16)
constexpr int DEPTH = 4;    // h ring depth
// x_bf group slice: placed at start of group g's OWN cT_b (o2) output slice.
// o2 slice per group = 64 rows * T * H * 4 B = 16 MB -> stride must be
// 16 MB = 2*ROWS*T*H bf16 elements (x_bf uses the first 8 MB of each slice).
constexpr size_t XBF_GSTRIDE = (size_t)2 * ROWS * T_ * H_;  // bf16 elements

DEV unsigned short f2bf(float f) {
  __hip_bfloat16 h = __float2bfloat16(f);
  return *reinterpret_cast<unsigned short*>(&h);
}
DEV float bf2f(unsigned short u) {
  __hip_bfloat16 h;
  *reinterpret_cast<unsigned short*>(&h) = u;
  return __bfloat162float(h);
}
DEV float sigm(float x) { return 1.0f / (1.0f + __expf(-x)); }
DEV float tanh_f(float x) {
  float e = __expf(-2.0f * fabsf(x));
  float t = (1.0f - e) / (1.0f + e);
  return copysignf(t, x);
}
DEV bfrag8 cvt_frag(const float* p) {
  float4 a = *reinterpret_cast<const float4*>(p);
  float4 b = *reinterpret_cast<const float4*>(p + 4);
  bfrag8 r;
  r[0] = (short)f2bf(a.x); r[1] = (short)f2bf(a.y);
  r[2] = (short)f2bf(a.z); r[3] = (short)f2bf(a.w);
  r[4] = (short)f2bf(b.x); r[5] = (short)f2bf(b.y);
  r[6] = (short)f2bf(b.z); r[7] = (short)f2bf(b.w);
  return r;
}

// ---- device-coherent (LLC) access helpers: proven R2/R3/R5/R6 ----
DEV void ld_sys_64B(const void* p, uint4& a, uint4& b, uint4& c, uint4& d) {
  asm volatile(
      "global_load_dwordx4 %0, %4, off sc0 sc1\n\t"
      "global_load_dwordx4 %1, %4, off offset:16 sc0 sc1\n\t"
      "global_load_dwordx4 %2, %4, off offset:32 sc0 sc1\n\t"
      "global_load_dwordx4 %3, %4, off offset:48 sc0 sc1\n\t"
      "s_waitcnt vmcnt(0)"
      : "=&v"(a), "=&v"(b), "=&v"(c), "=&v"(d) : "v"(p) : "memory");
}
DEV uint2 ld_sys_8B(const void* p) {
  uint2 r;
  asm volatile("global_load_dwordx2 %0, %1, off sc0 sc1\n\ts_waitcnt vmcnt(0)"
               : "=&v"(r) : "v"(p) : "memory");
  return r;
}
DEV void st_sys_u16(unsigned short* p, unsigned int v) {
  asm volatile("global_store_short %0, %1, off sc0 sc1" :: "v"(p), "v"(v) : "memory");
}
DEV void st_sys_u32(unsigned int* p, unsigned int v) {
  asm volatile("global_store_dword %0, %1, off sc0 sc1" :: "v"(p), "v"(v) : "memory");
}
DEV void drain_vm() { asm volatile("s_waitcnt vmcnt(0)" ::: "memory"); }
// R2-proven relaxed atomics (no cache-maintenance emitted)
DEV void arrive(int* p) {
  __hip_atomic_fetch_add(p, 1, __ATOMIC_RELAXED, __HIP_MEMORY_SCOPE_SYSTEM);
}
DEV int poll(const int* p) {
  return __hip_atomic_load(p, __ATOMIC_RELAXED, __HIP_MEMORY_SCOPE_SYSTEM);
}

// ---- prepass: x f32 -> bf16, group-local layout inside group's o2 slice ----
__global__ __launch_bounds__(256) void cvt_x_group(const float* __restrict__ x,
                                                   unsigned short* __restrict__ xbf) {
  int b = blockIdx.x;           // batch row 0..511
  int g = b >> 6, rl = b & 63;  // group, local row
  const float* src = x + (size_t)b * T_ * I_;
  unsigned short* dst = xbf + (size_t)g * XBF_GSTRIDE + (size_t)rl * T_ * I_;
  for (int i = threadIdx.x * 8; i < T_ * I_; i += 256 * 8) {
    float4 a = *reinterpret_cast<const float4*>(src + i);
    float4 c = *reinterpret_cast<const float4*>(src + i + 4);
    ushort4 p, q;
    p.x = f2bf(a.x); p.y = f2bf(a.y); p.z = f2bf(a.z); p.w = f2bf(a.w);
    q.x = f2bf(c.x); q.y = f2bf(c.y); q.z = f2bf(c.z); q.w = f2bf(c.w);
    *reinterpret_cast<ushort4*>(dst + i) = p;
    *reinterpret_cast<ushort4*>(dst + i + 4) = q;
  }
}

__global__ __launch_bounds__(NTHR, 2) void lstm_fused(
    const float* __restrict__ x, const unsigned short* __restrict__ x_bf,
    const int* __restrict__ is_init,
    const float* __restrict__ hx, const float* __restrict__ cx,
    const float* __restrict__ W_ih, const float* __restrict__ W_hh,
    const float* __restrict__ b_ih, const float* __restrict__ b_hh,
    const float* __restrict__ ln_w, const float* __restrict__ ln_b,
    float* __restrict__ out,
    unsigned short* __restrict__ hbuf, float* __restrict__ cts,
    int* __restrict__ cntg) {
  extern __shared__ char occupancy_pad[];          // 80 KB pad -> 1 block/CU
  __shared__ unsigned short wfr[2 * 16 * 64 * 8];  // W fragments, 32 KB
  __shared__ unsigned short In[64 * LDK2];         // h(t-1) tile (UNMASKED), 33 KB
  __shared__ float gat[64 * GLD];                  // gate exchange
  __shared__ float biasl[32];

  const int tid = threadIdx.x;
  const int g = blockIdx.x & 7;
  const int mem = blockIdx.x >> 3;   // member 0..31 within group
  const int rowbase = g * ROWS;
  const int jbase = mem * JPB;

  unsigned short* hb = hbuf + g * (DEPTH * ROWS * H_);
  int* cnt = cntg + g * 512;
  const unsigned short* xbg = x_bf + (size_t)g * XBF_GSTRIDE;  // [rl][t][i] bf16

  const int wv = tid >> 6;            // 0..7
  const int lane = tid & 63;
  const int mt = wv >> 1;             // M-tile 0..3
  const int nt = wv & 1;              // N-half 0..1
  const int kq = lane >> 4;           // k sub-chunk 0..3
  const int arow = mt * 16 + (lane & 15);  // A-frag batch row (local)
  const int row = tid >> 3;  // pointwise row 0..63
  const int seg = tid & 7;   // pointwise col 0..7

  float4 lnw4 = *reinterpret_cast<const float4*>(ln_w + lane * 4);
  float4 lnb4 = *reinterpret_cast<const float4*>(ln_b + lane * 4);

#define WFRAG(mat, m) (*reinterpret_cast<const bfrag8*>( \
    &wfr[(((mat) * 16 + (m) * 2 + nt) * 64 + lane) * 8]))

  // ---- prologue: stage W fragments into LDS (validated R5/R6 mapping) ----
  {
#pragma unroll
    for (int i2 = 0; i2 < 4; ++i2) {
      int fid = tid * 4 + i2;
      int lp = fid & 63;
      int m = (fid >> 6) & 7;
      int ntp = (fid >> 9) & 1;
      int mat = fid >> 10;
      int nn = ntp * 16 + (lp & 15);
      int kqp = lp >> 4;
      int growp = (nn >> 3) * 256 + jbase + (nn & 7);
      const float* src = (mat ? W_hh : W_ih) + growp * 256 + m * 32 + kqp * 8;
      *reinterpret_cast<bfrag8*>(&wfr[((mat * 16 + m * 2 + ntp) * 64 + lp) * 8]) =
          cvt_frag(src);
    }
  }
  if (tid < 32) {
    int gr2 = (tid >> 3) * 256 + jbase + (tid & 7);
    biasl[tid] = b_ih[gr2] + b_hh[gr2];
  }
  {  // publish h_{-1} = hx into ring slot 3
    int r = tid >> 8, cc = tid & 255;
    int lr = 2 * mem + r;
    st_sys_u16(hb + 3 * ROWS * H_ + lr * H_ + cc,
               (unsigned int)f2bf(hx[(size_t)(rowbase + lr) * H_ + cc]));
  }
  float creg = cx[(size_t)(rowbase + row) * H_ + jbase + seg];
  drain_vm();
  __syncthreads();
  if (tid == 0) arrive(&cnt[0]);

  // step-0: pointwise reset mask + x-projection from bf16 x (group-local)
  float rmP = is_init[(size_t)(rowbase + row) * T_ + 0] ? 0.f : 1.f;
  f32x4 accx = {0.f, 0.f, 0.f, 0.f};
  {
    const unsigned short* xb = xbg + ((size_t)arow * T_ + 0) * I_ + kq * 8;
#pragma unroll
    for (int m = 0; m < 8; ++m)
      accx = __builtin_amdgcn_mfma_f32_16x16x32_bf16(
          *reinterpret_cast<const bfrag8*>(xb + m * 32), WFRAG(0, m), accx, 0, 0, 0);
  }

  // ---- main loop over time ----
  for (int t = 0; t < T_; ++t) {
    // (A) loop-top issues (all long-latency, consumed late):
    int tn = (t + 1 < T_) ? t + 1 : t;
    bfrag8 xfr[8];  // x_bf A-frags for step t+1 (32 VGPRs)
    {
      const unsigned short* xb = xbg + ((size_t)arow * T_ + tn) * I_ + kq * 8;
#pragma unroll
      for (int m = 0; m < 8; ++m)
        xfr[m] = *reinterpret_cast<const bfrag8*>(xb + m * 32);
    }
    int iiP = is_init[(size_t)(rowbase + row) * T_ + tn];
    int iiA = is_init[(size_t)(rowbase + arow) * T_ + t];  // reset mask, step t
    float4 xskip;  // LN skip input for timestep t-1 (waves 0,1)
    if (t > 0 && wv < 2) {
      int gr = rowbase + 2 * mem + wv;
      xskip = *reinterpret_cast<const float4*>(
          x + ((size_t)gr * T_ + (t - 1)) * I_ + lane * 4);
    }

    // (B) wait until all 32 blocks published h_{t-1}
    if (tid == 0) {
      while (poll(&cnt[t]) < BPG) __builtin_amdgcn_s_sleep(1);
    }
    __syncthreads();

    const unsigned short* hbr = hb + ((t + 3) & 3) * (ROWS * H_);

    // (C) stage UNMASKED h_{t-1} -> In (coalesced 64B/lane LLC reads)
    {
      uint4 a, b, c, d;
      ld_sys_64B(hbr + row * H_ + seg * 32, a, b, c, d);
      uint4* dst = reinterpret_cast<uint4*>(In + row * LDK2 + seg * 32);
      dst[0] = a; dst[1] = b; dst[2] = c; dst[3] = d;
    }
    __syncthreads();

    // (D) h-part GEMM: A-frags from LDS with AND reset-mask; W_hh frags LDS
    f32x4 acc = accx;
    {
      const unsigned short* ab = In + (mt * 16 + (lane & 15)) * LDK2 + kq * 8;
      unsigned km = iiA ? 0u : 0xffffffffu;
#pragma unroll
      for (int m = 0; m < 8; ++m) {
        uint4 av = *reinterpret_cast<const uint4*>(ab + m * 32);
        av.x &= km; av.y &= km; av.z &= km; av.w &= km;
        acc = __builtin_amdgcn_mfma_f32_16x16x32_bf16(
            __builtin_bit_cast(bfrag8, av), WFRAG(1, m), acc, 0, 0, 0);
      }
    }
#pragma unroll
    for (int r = 0; r < 4; ++r)
      gat[(mt * 16 + kq * 4 + r) * GLD + nt * 16 + (lane & 15)] = acc[r];
    __syncthreads();

    // (E) pointwise cell update; publish h_t
    {
      float pi = gat[row * GLD + 0 + seg] + biasl[0 + seg];
      float pf = gat[row * GLD + 8 + seg] + biasl[8 + seg];
      float pg = gat[row * GLD + 16 + seg] + biasl[16 + seg];
      float po = gat[row * GLD + 24 + seg] + biasl[24 + seg];
      float ig = sigm(pi), fg = sigm(pf), gg = tanh_f(pg), og = sigm(po);
      creg = fg * (creg * rmP) + ig * gg;
      float hn = og * tanh_f(creg);
      st_sys_u16(hb + (t & 3) * (ROWS * H_) + row * H_ + jbase + seg,
                 (unsigned int)f2bf(hn));
    }
    drain_vm();
    __syncthreads();
    if (tid == 0) arrive(&cnt[t + 1]);

    // (F) shadow: x-projection for t+1 (frags preloaded); LN(t-1) from LDS
    rmP = iiP ? 0.f : 1.f;
    if (t + 1 < T_) {
      f32x4 ax = {0.f, 0.f, 0.f, 0.f};
#pragma unroll
      for (int m = 0; m < 8; ++m)
        ax = __builtin_amdgcn_mfma_f32_16x16x32_bf16(xfr[m], WFRAG(0, m), ax, 0, 0, 0);
      accx = ax;
    }
    if (t > 0 && wv < 2) {
      int lr = 2 * mem + wv;
      int gr = rowbase + lr;
      uint2 hv = *reinterpret_cast<const uint2*>(&In[lr * LDK2 + lane * 4]);
      float h0 = bf2f((unsigned short)(hv.x & 0xffff));
      float h1 = bf2f((unsigned short)(hv.x >> 16));
      float h2 = bf2f((unsigned short)(hv.y & 0xffff));
      float h3 = bf2f((unsigned short)(hv.y >> 16));
      float s = h0 + h1 + h2 + h3;
      float q = h0 * h0 + h1 * h1 + h2 * h2 + h3 * h3;
#pragma unroll
      for (int m = 1; m < 64; m <<= 1) {
        s += __shfl_xor(s, m);
        q += __shfl_xor(q, m);
      }
      float mu = s * (1.0f / 256.0f);
      float var = q * (1.0f / 256.0f) - mu * mu;
      float rs = rsqrtf(var + 1e-5f);
      float4 o4;
      o4.x = (h0 - mu) * rs * lnw4.x + lnb4.x + xskip.x;
      o4.y = (h1 - mu) * rs * lnw4.y + lnb4.y + xskip.y;
      o4.z = (h2 - mu) * rs * lnw4.z + lnb4.z + xskip.z;
      o4.w = (h3 - mu) * rs * lnw4.w + lnb4.w + xskip.w;
      *reinterpret_cast<float4*>(out + ((size_t)gr * T_ + (t - 1)) * H_ + lane * 4) = o4;
    }
  }

  // ---- epilogue ----
  if (tid == 0) {
    while (poll(&cnt[T_]) < BPG) __builtin_amdgcn_s_sleep(1);
  }
  __syncthreads();
  const unsigned short* hT = hb + ((T_ - 1) & 3) * (ROWS * H_);
  // LN for timestep T-1 (h_{T-1} from LLC ring slot; proven R6 path)
  if (wv < 2) {
    int lr = 2 * mem + wv;
    int gr = rowbase + lr;
    uint2 hv = ld_sys_8B(hT + lr * H_ + lane * 4);
    float h0 = bf2f((unsigned short)(hv.x & 0xffff));
    float h1 = bf2f((unsigned short)(hv.x >> 16));
    float h2 = bf2f((unsigned short)(hv.y & 0xffff));
    float h3 = bf2f((unsigned short)(hv.y >> 16));
    float s = h0 + h1 + h2 + h3;
    float q = h0 * h0 + h1 * h1 + h2 * h2 + h3 * h3;
#pragma unroll
    for (int m = 1; m < 64; m <<= 1) {
      s += __shfl_xor(s, m);
      q += __shfl_xor(q, m);
    }
    float mu = s * (1.0f / 256.0f);
    float var = q * (1.0f / 256.0f) - mu * mu;
    float rs = rsqrtf(var + 1e-5f);
    const float* xp = x + ((size_t)gr * T_ + (T_ - 1)) * I_ + lane * 4;
    float4 xv = *reinterpret_cast<const float4*>(xp);
    float4 o4;
    o4.x = (h0 - mu) * rs * lnw4.x + lnb4.x + xv.x;
    o4.y = (h1 - mu) * rs * lnw4.y + lnb4.y + xv.y;
    o4.z = (h2 - mu) * rs * lnw4.z + lnb4.z + xv.z;
    o4.w = (h3 - mu) * rs * lnw4.w + lnb4.w + xv.w;
    *reinterpret_cast<float4*>(out + ((size_t)gr * T_ + (T_ - 1)) * H_ + lane * 4) = o4;
  }
  st_sys_u32(reinterpret_cast<unsigned int*>(
                 cts + (size_t)(rowbase + row) * H_ + jbase + seg),
             __float_as_uint(creg));
  drain_vm();
  __syncthreads();
  if (tid == 0) {
    arrive(&cnt[T_ + 1]);
    while (poll(&cnt[T_ + 1]) < BPG) __builtin_amdgcn_s_sleep(1);
  }
  __syncthreads();
  {  // broadcast hT, cT over the T axis (own 2 rows; coalesced writes)
    int r = tid >> 8;
    int lr = 2 * mem + r;
    int gr = rowbase + lr;
    int c4 = (tid & 63) * 4;
    int tph = (tid >> 6) & 3;
    uint2 hu = ld_sys_8B(hT + lr * H_ + c4);
    float4 hv;
    hv.x = bf2f((unsigned short)(hu.x & 0xffff));
    hv.y = bf2f((unsigned short)(hu.x >> 16));
    hv.z = bf2f((unsigned short)(hu.y & 0xffff));
    hv.w = bf2f((unsigned short)(hu.y >> 16));
    uint2 ca = ld_sys_8B(cts + (size_t)gr * H_ + c4);
    uint2 cb = ld_sys_8B(cts + (size_t)gr * H_ + c4 + 2);
    float4 cv;
    cv.x = __uint_as_float(ca.x); cv.y = __uint_as_float(ca.y);
    cv.z = __uint_as_float(cb.x); cv.w = __uint_as_float(cb.y);
    float* o1 = out + (size_t)B_ * T_ * H_ + (size_t)gr * T_ * H_;
    float* o2 = o1 + (size_t)B_ * T_ * H_;
    for (int tt = tph; tt < T_; tt += 4) {
      *reinterpret_cast<float4*>(o1 + tt * H_ + c4) = hv;
      *reinterpret_cast<float4*>(o2 + tt * H_ + c4) = cv;
    }
  }
#undef WFRAG
}

extern "C" void kernel_launch(void* const* d_in, const int* in_sizes, int n_in,
                              void* d_out, int out_size, void* d_ws, size_t ws_size,
                              hipStream_t stream) {
  (void)in_sizes; (void)n_in; (void)out_size; (void)ws_size;
  const float* x = (const float*)d_in[0];
  const int* is_init = (const int*)d_in[1];
  const float* hx = (const float*)d_in[2];
  const float* cx = (const float*)d_in[3];
  const float* W_ih = (const float*)d_in[4];
  const float* W_hh = (const float*)d_in[5];
  const float* b_ih = (const float*)d_in[6];
  const float* b_hh = (const float*)d_in[7];
  const float* ln_w = (const float*)d_in[8];
  const float* ln_b = (const float*)d_in[9];
  float* out = (float*)d_out;

  char* ws = (char*)d_ws;
  unsigned short* hbuf = (unsigned short*)ws;          // 1 MB
  float* cts = (float*)(ws + (1 << 20));               // 512 KB
  int* cnt = (int*)(ws + (1 << 20) + (512 << 10));     // 8 * 512 ints

  // x_bf lives at the START of each group's OWN cT_b (o2) output slice:
  // o2 slice for group g = bytes [g*16MB, (g+1)*16MB) past out+2*B*T*H.
  // XBF_GSTRIDE = 16 MB in bf16 elements, so group g's x_bf (8 MB) sits
  // entirely inside its own slice. Group g reads only its slice during its
  // loop; only group g's epilogue (strictly after its loop) overwrites it.
  unsigned short* x_bf = (unsigned short*)(out + 2ull * B_ * T_ * H_);

  cvt_x_group<<<dim3(B_), dim3(256), 0, stream>>>(x, x_bf);
  hipMemsetAsync(cnt, 0, GROUPS * 512 * sizeof(int), stream);
  // ~74 KB static LDS + 80 KB dynamic pad -> 1 block/CU, 256 blocks resident.
  lstm_fused<<<dim3(GROUPS * BPG), dim3(NTHR), 81920, stream>>>(
      x, x_bf, is_init, hx, cx, W_ih, W_hh, b_ih, b_hh, ln_w, ln_b, out,
      hbuf, cts, cnt);
}

// Round 10
// 994.787 us; speedup vs baseline: 2.3752x; 1.3781x over previous
//
#include <hip/hip_runtime.h>
#include <hip/hip_bf16.h>

typedef __attribute__((ext_vector_type(8))) short bfrag8;
typedef __attribute__((ext_vector_type(4))) float f32x4;

#define DEV static __device__ __forceinline__

constexpr int B_ = 512, T_ = 256, I_ = 256, H_ = 256;
constexpr int GROUPS = 8, BPG = 32, ROWS = 64, JPB = 8;
constexpr int NTHR = 512;
constexpr int DEPTH = 4;    // h ring depth
constexpr size_t XBF_GSTRIDE = (size_t)2 * ROWS * T_ * H_;  // bf16 elems (16 MB)

DEV unsigned short f2bf(float f) {
  __hip_bfloat16 h = __float2bfloat16(f);
  return *reinterpret_cast<unsigned short*>(&h);
}
DEV float bf2f(unsigned short u) {
  __hip_bfloat16 h;
  *reinterpret_cast<unsigned short*>(&h) = u;
  return __bfloat162float(h);
}
DEV float sigm(float x) { return 1.0f / (1.0f + __expf(-x)); }
DEV float tanh_f(float x) {
  float e = __expf(-2.0f * fabsf(x));
  float t = (1.0f - e) / (1.0f + e);
  return copysignf(t, x);
}
DEV bfrag8 cvt_frag(const float* p) {
  float4 a = *reinterpret_cast<const float4*>(p);
  float4 b = *reinterpret_cast<const float4*>(p + 4);
  bfrag8 r;
  r[0] = (short)f2bf(a.x); r[1] = (short)f2bf(a.y);
  r[2] = (short)f2bf(a.z); r[3] = (short)f2bf(a.w);
  r[4] = (short)f2bf(b.x); r[5] = (short)f2bf(b.y);
  r[6] = (short)f2bf(b.z); r[7] = (short)f2bf(b.w);
  return r;
}

// ---- device-coherent (LLC) access helpers: proven R2/R3/R5/R6/R9 ----
DEV void ld_hfrag(const void* p, uint4& a0, uint4& a1, uint4& a2, uint4& a3,
                  uint4& a4, uint4& a5, uint4& a6, uint4& a7) {
  asm volatile(
      "global_load_dwordx4 %0, %8, off sc0 sc1\n\t"
      "global_load_dwordx4 %1, %8, off offset:64 sc0 sc1\n\t"
      "global_load_dwordx4 %2, %8, off offset:128 sc0 sc1\n\t"
      "global_load_dwordx4 %3, %8, off offset:192 sc0 sc1\n\t"
      "global_load_dwordx4 %4, %8, off offset:256 sc0 sc1\n\t"
      "global_load_dwordx4 %5, %8, off offset:320 sc0 sc1\n\t"
      "global_load_dwordx4 %6, %8, off offset:384 sc0 sc1\n\t"
      "global_load_dwordx4 %7, %8, off offset:448 sc0 sc1\n\t"
      "s_waitcnt vmcnt(0)"
      : "=&v"(a0), "=&v"(a1), "=&v"(a2), "=&v"(a3),
        "=&v"(a4), "=&v"(a5), "=&v"(a6), "=&v"(a7)
      : "v"(p)
      : "memory");
}
DEV uint2 ld_sys_8B(const void* p) {
  uint2 r;
  asm volatile("global_load_dwordx2 %0, %1, off sc0 sc1\n\ts_waitcnt vmcnt(0)"
               : "=&v"(r) : "v"(p) : "memory");
  return r;
}
DEV void st_sys_u16(unsigned short* p, unsigned int v) {
  asm volatile("global_store_short %0, %1, off sc0 sc1" :: "v"(p), "v"(v) : "memory");
}
DEV void st_sys_u32(unsigned int* p, unsigned int v) {
  asm volatile("global_store_dword %0, %1, off sc0 sc1" :: "v"(p), "v"(v) : "memory");
}
DEV void drain_vm() { asm volatile("s_waitcnt vmcnt(0)" ::: "memory"); }
DEV void arrive(int* p) {
  __hip_atomic_fetch_add(p, 1, __ATOMIC_RELAXED, __HIP_MEMORY_SCOPE_SYSTEM);
}
DEV int poll(const int* p) {
  return __hip_atomic_load(p, __ATOMIC_RELAXED, __HIP_MEMORY_SCOPE_SYSTEM);
}

// ---- prepass: x f32 -> bf16, group-local layout inside group's o2 slice ----
__global__ __launch_bounds__(256) void cvt_x_group(const float* __restrict__ x,
                                                   unsigned short* __restrict__ xbf) {
  int b = blockIdx.x;
  int g = b >> 6, rl = b & 63;
  const float* src = x + (size_t)b * T_ * I_;
  unsigned short* dst = xbf + (size_t)g * XBF_GSTRIDE + (size_t)rl * T_ * I_;
  for (int i = threadIdx.x * 8; i < T_ * I_; i += 256 * 8) {
    float4 a = *reinterpret_cast<const float4*>(src + i);
    float4 c = *reinterpret_cast<const float4*>(src + i + 4);
    ushort4 p, q;
    p.x = f2bf(a.x); p.y = f2bf(a.y); p.z = f2bf(a.z); p.w = f2bf(a.w);
    q.x = f2bf(c.x); q.y = f2bf(c.y); q.z = f2bf(c.z); q.w = f2bf(c.w);
    *reinterpret_cast<ushort4*>(dst + i) = p;
    *reinterpret_cast<ushort4*>(dst + i + 4) = q;
  }
}

__global__ __launch_bounds__(NTHR, 2) void lstm_fused(
    const float* __restrict__ x, const unsigned short* __restrict__ x_bf,
    const int* __restrict__ is_init,
    const float* __restrict__ hx, const float* __restrict__ cx,
    const float* __restrict__ W_ih, const float* __restrict__ W_hh,
    const float* __restrict__ b_ih, const float* __restrict__ b_hh,
    const float* __restrict__ ln_w, const float* __restrict__ ln_b,
    float* __restrict__ out,
    unsigned short* __restrict__ hbuf, float* __restrict__ cts,
    int* __restrict__ cntg) {
  extern __shared__ char occupancy_pad[];          // 80 KB pad -> 1 block/CU
  __shared__ unsigned short wfr[2 * 16 * 64 * 8];  // W fragments, 32 KB
  __shared__ f32x4 xacc[2][4][64][2];              // x-projection handoff, 16 KB
  __shared__ float biasl[32];

  const int tid = threadIdx.x;
  const int g = blockIdx.x & 7;
  const int mem = blockIdx.x >> 3;   // member 0..31 within group
  const int rowbase = g * ROWS;
  const int jbase = mem * JPB;

  unsigned short* hb = hbuf + g * (DEPTH * ROWS * H_);
  int* cnt = cntg + g * 512;
  const unsigned short* xbg = x_bf + (size_t)g * XBF_GSTRIDE;  // [rl][t][i]

  const int wv = tid >> 6;            // 0..7
  const int lane = tid & 63;
  const int c = lane & 15;            // col-in-half 0..15
  const int kq = lane >> 4;           // k sub-chunk / row-quad 0..3
  const int mt = wv & 3;              // M-tile (recurrence: wv, helper: wv-4)
  const int arow = mt * 16 + c;       // A-frag batch row (local)
  const int jl = c & 7;               // hidden col (local)
  const int selhi = c >> 3;           // 0: rows +0,1 ; 1: rows +2,3
  const int rowA = mt * 16 + kq * 4 + selhi * 2;  // pointwise row A (local)
  const int rowB = rowA + 1;
  const int jcol = jbase + jl;

  float4 lnw4 = *reinterpret_cast<const float4*>(ln_w + lane * 4);
  float4 lnb4 = *reinterpret_cast<const float4*>(ln_b + lane * 4);

  // W fragment macro: (mat, m, nth) -> bf16x8, lane-consecutive 16B
#define WFRAG(mat, m, nth) (*reinterpret_cast<const bfrag8*>( \
    &wfr[(((mat) * 16 + (m) * 2 + (nth)) * 64 + lane) * 8]))

  // ---- prologue: stage W fragments into LDS (validated R5/R6/R9 mapping) ----
  {
#pragma unroll
    for (int i2 = 0; i2 < 4; ++i2) {
      int fid = tid * 4 + i2;
      int lp = fid & 63;
      int m = (fid >> 6) & 7;
      int ntp = (fid >> 9) & 1;
      int mat = fid >> 10;
      int nn = ntp * 16 + (lp & 15);
      int kqp = lp >> 4;
      int growp = (nn >> 3) * 256 + jbase + (nn & 7);
      const float* src = (mat ? W_hh : W_ih) + growp * 256 + m * 32 + kqp * 8;
      *reinterpret_cast<bfrag8*>(&wfr[((mat * 16 + m * 2 + ntp) * 64 + lp) * 8]) =
          cvt_frag(src);
    }
  }
  if (tid < 32) {
    int gr2 = (tid >> 3) * 256 + jbase + (tid & 7);
    biasl[tid] = b_ih[gr2] + b_hh[gr2];
  }
  // per-lane biases for pointwise (4 gates of jcol)
  float bi = b_ih[0 * 256 + jcol] + b_hh[0 * 256 + jcol];
  float bf = b_ih[1 * 256 + jcol] + b_hh[1 * 256 + jcol];
  float bg = b_ih[2 * 256 + jcol] + b_hh[2 * 256 + jcol];
  float bo = b_ih[3 * 256 + jcol] + b_hh[3 * 256 + jcol];
  {  // publish h_{-1} = hx into ring slot 3
    int r = tid >> 8, cc = tid & 255;
    int lr = 2 * mem + r;
    st_sys_u16(hb + 3 * ROWS * H_ + lr * H_ + cc,
               (unsigned int)f2bf(hx[(size_t)(rowbase + lr) * H_ + cc]));
  }
  // recurrence cell state (2 rows per lane)
  float cregA = cx[(size_t)(rowbase + rowA) * H_ + jcol];
  float cregB = cx[(size_t)(rowbase + rowB) * H_ + jcol];
  drain_vm();
  __syncthreads();
  if (tid == 0) arrive(&cnt[0]);

  // helpers: xacc(0) = x_0 . W_ih (wfr staged pre-barrier)
  if (wv >= 4) {
    const unsigned short* xb = xbg + ((size_t)arow * T_ + 0) * I_ + kq * 8;
    f32x4 a0 = {0.f, 0.f, 0.f, 0.f}, a1 = {0.f, 0.f, 0.f, 0.f};
#pragma unroll
    for (int m = 0; m < 8; ++m) {
      bfrag8 xf = *reinterpret_cast<const bfrag8*>(xb + m * 32);
      a0 = __builtin_amdgcn_mfma_f32_16x16x32_bf16(xf, WFRAG(0, m, 0), a0, 0, 0, 0);
      a1 = __builtin_amdgcn_mfma_f32_16x16x32_bf16(xf, WFRAG(0, m, 1), a1, 0, 0, 0);
    }
    xacc[0][mt][lane][0] = a0;
    xacc[0][mt][lane][1] = a1;
  }

  // ---- main loop over time ----
  for (int t = 0; t < T_; ++t) {
    // per-wave pre-issue (no barriers inside)
    int iiA = 0, iiPA = 0, iiPB = 0;
    bfrag8 xf[8];
    float4 xskip;
    if (wv < 4) {
      iiA = is_init[(size_t)(rowbase + arow) * T_ + t];
      iiPA = is_init[(size_t)(rowbase + rowA) * T_ + t];
      iiPB = is_init[(size_t)(rowbase + rowB) * T_ + t];
    } else {
      int tn = (t + 1 < T_) ? t + 1 : t;
      const unsigned short* xb = xbg + ((size_t)arow * T_ + tn) * I_ + kq * 8;
#pragma unroll
      for (int m = 0; m < 8; ++m)
        xf[m] = *reinterpret_cast<const bfrag8*>(xb + m * 32);
      if (t > 0 && wv < 6) {
        int gr = rowbase + 2 * mem + (wv - 4);
        xskip = *reinterpret_cast<const float4*>(
            x + ((size_t)gr * T_ + (t - 1)) * I_ + lane * 4);
      }
    }

    // (B) wait until all 32 blocks published h_{t-1}
    if (tid == 0) {
      while (poll(&cnt[t]) < BPG) __builtin_amdgcn_s_sleep(1);
    }
    __syncthreads();  // S1

    const unsigned short* hbr = hb + ((t + 3) & 3) * (ROWS * H_);

    if (wv < 4) {
      // ---- recurrence critical path ----
      // A-frags direct from LLC (each byte of h read once per wave-quad)
      uint4 h0, h1, h2, h3, h4, h5, h6, h7;
      ld_hfrag(hbr + arow * H_ + kq * 8, h0, h1, h2, h3, h4, h5, h6, h7);
      unsigned km = iiA ? 0u : 0xffffffffu;
#define MASK4(v) v.x &= km; v.y &= km; v.z &= km; v.w &= km
      MASK4(h0); MASK4(h1); MASK4(h2); MASK4(h3);
      MASK4(h4); MASK4(h5); MASK4(h6); MASK4(h7);
#undef MASK4
      f32x4 acc0 = xacc[t & 1][mt][lane][0];
      f32x4 acc1 = xacc[t & 1][mt][lane][1];
#define HM(v, m) \
      acc0 = __builtin_amdgcn_mfma_f32_16x16x32_bf16(__builtin_bit_cast(bfrag8, v), WFRAG(1, m, 0), acc0, 0, 0, 0); \
      acc1 = __builtin_amdgcn_mfma_f32_16x16x32_bf16(__builtin_bit_cast(bfrag8, v), WFRAG(1, m, 1), acc1, 0, 0, 0)
      HM(h0, 0); HM(h1, 1); HM(h2, 2); HM(h3, 3);
      HM(h4, 4); HM(h5, 5); HM(h6, 6); HM(h7, 7);
#undef HM
      // gate exchange: partner lane (c^8) holds the other two gates
      f32x4 po0, po1;
#pragma unroll
      for (int r = 0; r < 4; ++r) {
        po0[r] = __shfl_xor(acc0[r], 8);
        po1[r] = __shfl_xor(acc1[r], 8);
      }
      float iA, iB, fA, fB, gA, gB, oA, oB;
      if (selhi == 0) {  // own: i (acc0), g (acc1); partner: f, o ; rows +0,+1
        iA = acc0[0]; iB = acc0[1]; gA = acc1[0]; gB = acc1[1];
        fA = po0[0];  fB = po0[1];  oA = po1[0];  oB = po1[1];
      } else {           // own: f (acc0), o (acc1); partner: i, g ; rows +2,+3
        fA = acc0[2]; fB = acc0[3]; oA = acc1[2]; oB = acc1[3];
        iA = po0[2];  iB = po0[3];  gA = po1[2];  gB = po1[3];
      }
      // pointwise (2 rows) + publish h_t
      unsigned short* hbw = hb + (t & 3) * (ROWS * H_);
      {
        float ig = sigm(iA + bi), fg = sigm(fA + bf);
        float gg = tanh_f(gA + bg), og = sigm(oA + bo);
        float rm = iiPA ? 0.f : 1.f;
        cregA = fg * (cregA * rm) + ig * gg;
        st_sys_u16(hbw + rowA * H_ + jcol, (unsigned int)f2bf(og * tanh_f(cregA)));
      }
      {
        float ig = sigm(iB + bi), fg = sigm(fB + bf);
        float gg = tanh_f(gB + bg), og = sigm(oB + bo);
        float rm = iiPB ? 0.f : 1.f;
        cregB = fg * (cregB * rm) + ig * gg;
        st_sys_u16(hbw + rowB * H_ + jcol, (unsigned int)f2bf(og * tanh_f(cregB)));
      }
      drain_vm();
    } else {
      // ---- helpers: xacc(t+1) + LN(t-1) ----
      if (t + 1 < T_) {
        f32x4 a0 = {0.f, 0.f, 0.f, 0.f}, a1 = {0.f, 0.f, 0.f, 0.f};
#pragma unroll
        for (int m = 0; m < 8; ++m) {
          a0 = __builtin_amdgcn_mfma_f32_16x16x32_bf16(xf[m], WFRAG(0, m, 0), a0, 0, 0, 0);
          a1 = __builtin_amdgcn_mfma_f32_16x16x32_bf16(xf[m], WFRAG(0, m, 1), a1, 0, 0, 0);
        }
        xacc[(t + 1) & 1][mt][lane][0] = a0;
        xacc[(t + 1) & 1][mt][lane][1] = a1;
      }
      if (t > 0 && wv < 6) {  // LN(t-1) + x skip, rows 2*mem, 2*mem+1
        int lr = 2 * mem + (wv - 4);
        int gr = rowbase + lr;
        uint2 hv = ld_sys_8B(hbr + lr * H_ + lane * 4);
        float h0v = bf2f((unsigned short)(hv.x & 0xffff));
        float h1v = bf2f((unsigned short)(hv.x >> 16));
        float h2v = bf2f((unsigned short)(hv.y & 0xffff));
        float h3v = bf2f((unsigned short)(hv.y >> 16));
        float s = h0v + h1v + h2v + h3v;
        float q = h0v * h0v + h1v * h1v + h2v * h2v + h3v * h3v;
#pragma unroll
        for (int m = 1; m < 64; m <<= 1) {
          s += __shfl_xor(s, m);
          q += __shfl_xor(q, m);
        }
        float mu = s * (1.0f / 256.0f);
        float var = q * (1.0f / 256.0f) - mu * mu;
        float rs = rsqrtf(var + 1e-5f);
        float4 o4;
        o4.x = (h0v - mu) * rs * lnw4.x + lnb4.x + xskip.x;
        o4.y = (h1v - mu) * rs * lnw4.y + lnb4.y + xskip.y;
        o4.z = (h2v - mu) * rs * lnw4.z + lnb4.z + xskip.z;
        o4.w = (h3v - mu) * rs * lnw4.w + lnb4.w + xskip.w;
        *reinterpret_cast<float4*>(out + ((size_t)gr * T_ + (t - 1)) * H_ + lane * 4) = o4;
      }
    }
    __syncthreads();  // S2
    if (tid == 0) arrive(&cnt[t + 1]);
  }

  // ---- epilogue ----
  if (tid == 0) {
    while (poll(&cnt[T_]) < BPG) __builtin_amdgcn_s_sleep(1);
  }
  __syncthreads();
  const unsigned short* hT = hb + ((T_ - 1) & 3) * (ROWS * H_);
  // LN for timestep T-1 (proven R6/R9 path)
  if (wv < 2) {
    int lr = 2 * mem + wv;
    int gr = rowbase + lr;
    uint2 hv = ld_sys_8B(hT + lr * H_ + lane * 4);
    float h0v = bf2f((unsigned short)(hv.x & 0xffff));
    float h1v = bf2f((unsigned short)(hv.x >> 16));
    float h2v = bf2f((unsigned short)(hv.y & 0xffff));
    float h3v = bf2f((unsigned short)(hv.y >> 16));
    float s = h0v + h1v + h2v + h3v;
    float q = h0v * h0v + h1v * h1v + h2v * h2v + h3v * h3v;
#pragma unroll
    for (int m = 1; m < 64; m <<= 1) {
      s += __shfl_xor(s, m);
      q += __shfl_xor(q, m);
    }
    float mu = s * (1.0f / 256.0f);
    float var = q * (1.0f / 256.0f) - mu * mu;
    float rs = rsqrtf(var + 1e-5f);
    const float* xp = x + ((size_t)gr * T_ + (T_ - 1)) * I_ + lane * 4;
    float4 xv = *reinterpret_cast<const float4*>(xp);
    float4 o4;
    o4.x = (h0v - mu) * rs * lnw4.x + lnb4.x + xv.x;
    o4.y = (h1v - mu) * rs * lnw4.y + lnb4.y + xv.y;
    o4.z = (h2v - mu) * rs * lnw4.z + lnb4.z + xv.z;
    o4.w = (h3v - mu) * rs * lnw4.w + lnb4.w + xv.w;
    *reinterpret_cast<float4*>(out + ((size_t)gr * T_ + (T_ - 1)) * H_ + lane * 4) = o4;
  }
  if (wv < 4) {  // final cell state
    st_sys_u32(reinterpret_cast<unsigned int*>(
                   cts + (size_t)(rowbase + rowA) * H_ + jcol),
               __float_as_uint(cregA));
    st_sys_u32(reinterpret_cast<unsigned int*>(
                   cts + (size_t)(rowbase + rowB) * H_ + jcol),
               __float_as_uint(cregB));
  }
  drain_vm();
  __syncthreads();
  if (tid == 0) {
    arrive(&cnt[T_ + 1]);
    while (poll(&cnt[T_ + 1]) < BPG) __builtin_amdgcn_s_sleep(1);
  }
  __syncthreads();
  {  // broadcast hT, cT over the T axis (own 2 rows; coalesced writes)
    int r = tid >> 8;
    int lr = 2 * mem + r;
    int gr = rowbase + lr;
    int c4 = (tid & 63) * 4;
    int tph = (tid >> 6) & 3;
    uint2 hu = ld_sys_8B(hT + lr * H_ + c4);
    float4 hv;
    hv.x = bf2f((unsigned short)(hu.x & 0xffff));
    hv.y = bf2f((unsigned short)(hu.x >> 16));
    hv.z = bf2f((unsigned short)(hu.y & 0xffff));
    hv.w = bf2f((unsigned short)(hu.y >> 16));
    uint2 ca = ld_sys_8B(cts + (size_t)gr * H_ + c4);
    uint2 cb = ld_sys_8B(cts + (size_t)gr * H_ + c4 + 2);
    float4 cv;
    cv.x = __uint_as_float(ca.x); cv.y = __uint_as_float(ca.y);
    cv.z = __uint_as_float(cb.x); cv.w = __uint_as_float(cb.y);
    float* o1 = out + (size_t)B_ * T_ * H_ + (size_t)gr * T_ * H_;
    float* o2 = o1 + (size_t)B_ * T_ * H_;
    for (int tt = tph; tt < T_; tt += 4) {
      *reinterpret_cast<float4*>(o1 + tt * H_ + c4) = hv;
      *reinterpret_cast<float4*>(o2 + tt * H_ + c4) = cv;
    }
  }
#undef WFRAG
}

extern "C" void kernel_launch(void* const* d_in, const int* in_sizes, int n_in,
                              void* d_out, int out_size, void* d_ws, size_t ws_size,
                              hipStream_t stream) {
  (void)in_sizes; (void)n_in; (void)out_size; (void)ws_size;
  const float* x = (const float*)d_in[0];
  const int* is_init = (const int*)d_in[1];
  const float* hx = (const float*)d_in[2];
  const float* cx = (const float*)d_in[3];
  const float* W_ih = (const float*)d_in[4];
  const float* W_hh = (const float*)d_in[5];
  const float* b_ih = (const float*)d_in[6];
  const float* b_hh = (const float*)d_in[7];
  const float* ln_w = (const float*)d_in[8];
  const float* ln_b = (const float*)d_in[9];
  float* out = (float*)d_out;

  char* ws = (char*)d_ws;
  unsigned short* hbuf = (unsigned short*)ws;          // 1 MB
  float* cts = (float*)(ws + (1 << 20));               // 512 KB
  int* cnt = (int*)(ws + (1 << 20) + (512 << 10));     // 8 * 512 ints

  // x_bf inside each group's OWN o2 output slice (16 MB stride; first 8 MB).
  unsigned short* x_bf = (unsigned short*)(out + 2ull * B_ * T_ * H_);

  cvt_x_group<<<dim3(B_), dim3(256), 0, stream>>>(x, x_bf);
  hipMemsetAsync(cnt, 0, GROUPS * 512 * sizeof(int), stream);
  // ~49 KB static LDS + 80 KB pad -> 1 block/CU, 256 blocks resident.
  lstm_fused<<<dim3(GROUPS * BPG), dim3(NTHR), 81920, stream>>>(
      x, x_bf, is_init, hx, cx, W_ih, W_hh, b_ih, b_hh, ln_w, ln_b, out,
      hbuf, cts, cnt);
}